// Round 20
// baseline (614.395 us; speedup 1.0000x reference)
//
#include <hip/hip_runtime.h>
#include <hip/hip_bf16.h>

typedef unsigned int u32;
typedef unsigned short u16;
typedef __attribute__((ext_vector_type(8))) short bf16x8;   // 8 bf16 = 4 VGPRs
typedef __attribute__((ext_vector_type(4))) float f32x4;

#define DEVI __device__ __forceinline__

constexpr int AG = 8, H = 100, W = 352, HP = 102, WP = 354;
constexpr int HWp = H * W;          // 35200
constexpr int NB = 2 * WP + 2 * H;  // 908 border pixels per agent

DEVI u16 f2bf(float f) {
  __hip_bfloat16 h = __float2bfloat16(f);
  return *reinterpret_cast<u16*>(&h);
}
DEVI float bf2f(u16 v) { return __uint_as_float(((u32)v) << 16); }

// interleaved channel order within each 32-block: stored 8v+j <-> logical
// {4v+j (j<4), 16+4v+(j-4) (j>=4)} so one 16B unit = one MFMA k-fragment.
DEVI int chperm(int j) { int v = j >> 3, r = j & 7; return (r < 4) ? 4 * v + r : 16 + 4 * v + (r - 4); }
DEVI int chlog(int c) { return (c & ~31) + chperm(c & 31); }

typedef __attribute__((address_space(1))) const u32 as1c_u32;
typedef __attribute__((address_space(3))) u32 as3_u32;
DEVI void gload16(const u16* g, u16* l) {
  __builtin_amdgcn_global_load_lds((as1c_u32*)(const void*)g, (as3_u32*)(void*)l, 16, 0, 0);
}

template <int N> DEVI void waitcnt_vm() {
  if constexpr (N == 0) asm volatile("s_waitcnt vmcnt(0)" ::: "memory");
  else if constexpr (N == 3) asm volatile("s_waitcnt vmcnt(3)" ::: "memory");
  else if constexpr (N == 4) asm volatile("s_waitcnt vmcnt(4)" ::: "memory");
  else asm volatile("s_waitcnt vmcnt(0)" ::: "memory");
}

// ---------------------------------------------------------------------------
// XCD-striped packed worklists. Item = (box<<6)|(chunk<<1)|cb, emitted at
// stripe position xcd + 8*off where xcd = box&7: the hardware round-robins
// consecutive blockIdx across the 8 XCDs, so all of a box's blocks land on
// ONE XCD (L2 locality) while boxes spread evenly (balance). Pads (-1) sit
// at stripe tails. Layer geometry MUST match the conv kernels:
//   L0..L3 (1a,1b,2a,2b; NC=1): npx = clamp(box+HALO), HALO=6,5,4,3
//   L4 (3a): (bw+4)^2-ish; L5 (3b): (bw+2)..; L6 (Da): bw*bh   (NC=2 each)
constexpr int WL_MAXCH[7] = {7, 6, 5, 4, 4, 3, 2};
constexpr int WL_NC[7] = {1, 1, 1, 1, 2, 2, 2};
__global__ void build_wl(const int* __restrict__ boxes, int nbox,
                         int* __restrict__ wl) {
  __shared__ int ent[7][512];   // entries (chunks*NC) per box
  __shared__ int pos[7][512];   // within-xcd exclusive offset
  __shared__ int base_l[8];
  int t = threadIdx.x;
  int nbox8 = (nbox + 7) & ~7;
  if (t == 0) {
    int b = 0;
    for (int l = 0; l < 7; ++l) { base_l[l] = b; b += nbox8 * WL_MAXCH[l] * WL_NC[l]; }
    base_l[7] = b;
  }
  __syncthreads();
  int total = base_l[7];
  for (int i = t; i < total; i += 512) wl[i] = -1;  // pad
  if (t < nbox) {
    const int* bx = boxes + t * 4;
    int bw = bx[1] - bx[0], bh = bx[3] - bx[2];
#pragma unroll
    for (int l = 0; l < 4; ++l) {
      int halo = 6 - l;
      int cl = max(bx[0] - halo, 0), cr = min(bx[1] + halo, W);
      int r0 = max(bx[2] - halo, 0), r1 = min(bx[3] + halo, H);
      ent[l][t] = min(((cr - cl) * (r1 - r0) + 127) >> 7, WL_MAXCH[l]);
    }
    ent[4][t] = min(((bw + 4) * (bh + 4) + 127) >> 7, 4) * 2;
    ent[5][t] = min(((bw + 2) * (bh + 2) + 127) >> 7, 3) * 2;
    ent[6][t] = min((bw * bh + 127) >> 7, 2) * 2;
  }
  __syncthreads();
  if (t == 0) {  // deterministic per-(layer,xcd) exclusive scan
    for (int l = 0; l < 7; ++l) {
      int run[8] = {0, 0, 0, 0, 0, 0, 0, 0};
      for (int b = 0; b < nbox; ++b) {
        int x = b & 7;
        pos[l][b] = run[x];
        run[x] += ent[l][b];
      }
    }
  }
  __syncthreads();
  if (t < nbox) {
    const int* bx = boxes + t * 4;
    int bw = bx[1] - bx[0], bh = bx[3] - bx[2];
    int nc[7];
#pragma unroll
    for (int l = 0; l < 4; ++l) {
      int halo = 6 - l;
      int cl = max(bx[0] - halo, 0), cr = min(bx[1] + halo, W);
      int r0 = max(bx[2] - halo, 0), r1 = min(bx[3] + halo, H);
      nc[l] = min(((cr - cl) * (r1 - r0) + 127) >> 7, WL_MAXCH[l]);
    }
    nc[4] = min(((bw + 4) * (bh + 4) + 127) >> 7, 4);
    nc[5] = min(((bw + 2) * (bh + 2) + 127) >> 7, 3);
    nc[6] = min((bw * bh + 127) >> 7, 2);
    int x = t & 7;
#pragma unroll
    for (int l = 0; l < 7; ++l) {
      int off = pos[l][t];
      for (int c = 0; c < nc[l]; ++c)
        for (int cbv = 0; cbv < WL_NC[l]; ++cbv)
          wl[base_l[l] + x + 8 * (off++)] = (t << 6) | (c << 1) | cbv;
    }
  }
}

// ---------------------------------------------------------------------------
// feature slice fp32 NCHW -> padded NHWC(permuted) bf16 interior, via LDS
// transpose. grid: aloc*H*11 blocks; block 256 thr.
__global__ void convert_feat(const float* __restrict__ f, u16* __restrict__ dst) {
  __shared__ float t32[64][33];
  int blk = blockIdx.x;
  int wseg = blk % 11;
  int rest = blk / 11;
  int h = rest % H;
  int a = rest / H;
  int t = threadIdx.x;
  int wbase = wseg * 32;
  {
    int w = t & 31;
    int c0 = (t >> 5) * 8;
#pragma unroll
    for (int i = 0; i < 8; ++i) {
      int lc = c0 + i;
      t32[lc][w] = f[((size_t)(a * 64 + lc) * H + h) * W + wbase + w];
    }
  }
  __syncthreads();
  int p = t >> 3;
  int cs = (t & 7) * 8;
  u16 tmp[8];
#pragma unroll
  for (int j = 0; j < 8; ++j) {
    int c = cs + j;
    int lc = (c & 32) + chperm(c & 31);
    tmp[j] = f2bf(t32[lc][p]);
  }
  size_t ob = ((size_t)(a * HP + h + 1) * WP + (wbase + p + 1)) * 64 + cs;
  *reinterpret_cast<uint4*>(dst + ob) = *reinterpret_cast<uint4*>(tmp);
}

// zero the 1-pixel border of a padded NHWC buffer with C channels, nA agents
template <int C>
__global__ void zero_border(u16* __restrict__ buf, int nA) {
  constexpr int CH = C / 8;
  int idx = blockIdx.x * 256 + threadIdx.x;
  int pix = idx / CH;
  int cc = (idx - pix * CH) * 8;
  if (pix >= nA * NB) return;
  int a = pix / NB;
  int b = pix - a * NB;
  int h, w;
  if (b < WP) { h = 0; w = b; }
  else if (b < 2 * WP) { h = HP - 1; w = b - WP; }
  else {
    int bb = b - 2 * WP;
    int bb2 = (bb < H) ? bb : bb - H;
    h = 1 + bb2;
    w = (bb < H) ? 0 : (WP - 1);
  }
  size_t off = ((size_t)(a * HP + h) * WP + w) * C + cc;
  *reinterpret_cast<uint4*>(buf + off) = make_uint4(0u, 0u, 0u, 0u);
}

// w [O][I][kh][kw] fp32 -> rp[s=t*KB+kb][r:O][u:8][jj:8] bf16 with the LDS
// row-XOR swizzle baked in: stored (r,u) holds logical unit lu = u^(r&7).
__global__ void repack_w(const float* __restrict__ w, u16* __restrict__ rp,
                         int O, int I, int taps) {
  int idx = blockIdx.x * 256 + threadIdx.x;
  int total = O * I * taps;
  if (idx >= total) return;
  int jj = idx & 7;
  int u = (idx >> 3) & 7;
  int r = (idx >> 6) % O;
  int s = idx / (O * 64);
  int KB = I >> 6;
  int kb = s % KB;
  int t = s / KB;
  int lu = u ^ (r & 7);
  int g = lu & 3, j32 = lu >> 2;
  int cp = (jj < 4) ? 4 * g + jj : 16 + 4 * g + (jj - 4);
  int i = kb * 64 + j32 * 32 + cp;
  int o = (r & ~31) + chperm(r & 31);
  rp[idx] = f2bf(w[((size_t)o * I + i) * taps + t]);
}

// 1x1 weight [256][256] fp32 -> plain rp[kb32:8][r:256][g:4][jj:8]
__global__ void repack_plain(const float* __restrict__ w, u16* __restrict__ rp) {
  int idx = blockIdx.x * 256 + threadIdx.x;  // 65536 total
  int jj = idx & 7;
  int g = (idx >> 3) & 3;
  int r = (idx >> 5) & 255;
  int kb = idx >> 13;
  int cp = (jj < 4) ? 4 * g + jj : 16 + 4 * g + (jj - 4);
  int i = kb * 32 + cp;
  int o = chlog(r);
  rp[idx] = f2bf(w[(size_t)o * 256 + i]);
}

// ---------------------------------------------------------------------------
// Box-restricted 3x3 conv on full padded maps (round-16 proven inner loop):
// BK=64, 64KB dbuf LDS, half-split staging, counted vmcnt, setprio.
// XCD-striped worklist via raw blockIdx (balance + per-box L2 locality).
template <int CIN, int COUT, int MAXCH, int HALO>
__global__ __launch_bounds__(256, 2) void conv_boxk(
    const u16* __restrict__ in, const u16* __restrict__ wrp,
    const float* __restrict__ bias, u16* __restrict__ out,
    const int* __restrict__ boxes, const int* __restrict__ wl, int wbase) {
  constexpr int BM = 128, BN = 128, BK = 64, TAPS = 9;
  constexpr int KB = CIN / BK;
  constexpr int KS = TAPS * KB;
  constexpr int NT = 256;
  constexpr int ACH = 4, AH = 2, BH = 2, HALF = 4;
  constexpr int ASZ = BM * BK;
  constexpr int BSZ = BN * BK;
  __shared__ u16 smem[2 * (ASZ + BSZ)];  // 64 KB

  const int item = wl[wbase + blockIdx.x];
  if (item < 0) return;
  const int box = item >> 6;
  const int c0 = (item >> 1) & 31;
  const int cb = item & 1;  // 0 for COUT=128 layers
  const int* bx = boxes + box * 4;
  const int a = box / 50;
  const int cl = max(bx[0] - HALO, 0);
  const int cr = min(bx[1] + HALO, W);
  const int r0 = max(bx[2] - HALO, 0);
  const int r1 = min(bx[3] + HALO, H);
  const int bw = cr - cl;
  const int npx = bw * (r1 - r0);

  const int tid = threadIdx.x;
  const int lane = tid & 63;
  const int wid = tid >> 6;
  const int wr = wid >> 1;
  const int wc = wid & 1;

  int aoff[ACH];
#pragma unroll
  for (int i = 0; i < ACH; ++i) {
    int c = tid + i * NT;
    int p = c >> 3, u = c & 7;
    int lu = u ^ (p & 7);
    int idx = c0 * 128 + p;
    if (idx >= npx) idx = npx - 1;
    int ph = r0 + idx / bw;
    int pw = cl + idx % bw;
    aoff[i] = ((a * HP + ph + 1) * WP + (pw + 1)) * CIN + lu * 8;
  }

  f32x4 acc[4][4];
#pragma unroll
  for (int m = 0; m < 4; ++m)
#pragma unroll
    for (int n = 0; n < 4; ++n) acc[m][n] = f32x4{0.f, 0.f, 0.f, 0.f};

  const int g = lane >> 4;
  const int arow = lane & 15;
  const int fk = arow & 7;

  auto stage = [&](int s, int h) {
    int par = s & 1;
    u16* Ad = smem + par * ASZ;
    u16* Bd = smem + 2 * ASZ + par * BSZ;
    int t = s / KB;
    int kb = s - t * KB;
    int doff = kb * BK + ((t / 3 - 1) * WP + (t % 3 - 1)) * CIN;
    const u16* wtile = wrp + (size_t)s * (COUT * BK) + cb * BSZ;
#pragma unroll
    for (int i = h * AH; i < h * AH + AH; ++i)
      gload16(in + aoff[i] + doff, Ad + (tid + i * NT) * 8);
#pragma unroll
    for (int i = h * BH; i < h * BH + BH; ++i)
      gload16(wtile + (tid + i * NT) * 8, Bd + (tid + i * NT) * 8);
  };

  stage(0, 0);
  stage(0, 1);

  for (int s = 0; s < KS; ++s) {
    int par = s & 1;
    const u16* Ab = smem + par * ASZ;
    const u16* Bb = smem + 2 * ASZ + par * BSZ;
    if (s + 1 < KS) {
      stage(s + 1, 0);
      waitcnt_vm<HALF>();
    } else {
      waitcnt_vm<0>();
    }
    __builtin_amdgcn_s_barrier();

#pragma unroll
    for (int j = 0; j < 2; ++j) {
      bf16x8 af[4], bfr[4];
#pragma unroll
      for (int m = 0; m < 4; ++m)
        af[m] = *reinterpret_cast<const bf16x8*>(
            Ab + (wr * 64 + m * 16 + arow) * 64 + (((j * 4 + g) ^ fk) << 3));
#pragma unroll
      for (int n = 0; n < 4; ++n)
        bfr[n] = *reinterpret_cast<const bf16x8*>(
            Bb + (wc * 64 + n * 16 + arow) * 64 + (((j * 4 + g) ^ fk) << 3));
      __builtin_amdgcn_s_setprio(1);
#pragma unroll
      for (int m = 0; m < 4; ++m)
#pragma unroll
        for (int n = 0; n < 4; ++n)
          acc[m][n] = __builtin_amdgcn_mfma_f32_16x16x32_bf16(af[m], bfr[n], acc[m][n], 0, 0, 0);
      __builtin_amdgcn_s_setprio(0);
      if (j == 0 && s + 1 < KS) stage(s + 1, 1);
    }
    __builtin_amdgcn_s_barrier();
  }

  __syncthreads();
  float bs[4];
#pragma unroll
  for (int n = 0; n < 4; ++n) bs[n] = bias[chlog(cb * BN + wc * 64 + n * 16 + arow)];
  u16* et = smem + wid * 2048;
#pragma unroll
  for (int pp = 0; pp < 2; ++pp) {
    if (pp) __syncthreads();
#pragma unroll
    for (int mm = 0; mm < 2; ++mm) {
      int m = pp * 2 + mm;
#pragma unroll
      for (int rg = 0; rg < 4; ++rg) {
        int row = mm * 16 + g * 4 + rg;
#pragma unroll
        for (int n = 0; n < 4; ++n) {
          int col = (n * 16 + arow) ^ (g << 4);
          et[row * 64 + col] = f2bf(fmaxf(acc[m][n][rg] + bs[n], 0.f));
        }
      }
    }
    __syncthreads();
#pragma unroll
    for (int jj = 0; jj < 4; ++jj) {
      int p = jj * 8 + (lane >> 3);
      int un = lane & 7;
      int su = un ^ (((p >> 2) & 3) << 1);
      uint4 qv = *reinterpret_cast<const uint4*>(et + p * 64 + su * 8);
      int idx = c0 * 128 + wr * 64 + pp * 32 + p;
      if (idx >= npx) idx = npx - 1;  // dup writes, same value
      int ph = r0 + idx / bw;
      int pw = cl + idx % bw;
      size_t ob = ((size_t)(a * HP + ph + 1) * WP + (pw + 1)) * COUT +
                  cb * BN + wc * 64 + un * 8;
      *reinterpret_cast<uint4*>(out + ob) = qv;
    }
  }
}

// ---------------------------------------------------------------------------
// Tile-pipeline conv for the tail (COUT=256). Variable per-box extents,
// fixed slot strides (400/324/256). Round-16 dbuf pipeline + XCD-striped
// worklist via raw blockIdx.
template <int CIN, int EOUT, int MAXCH, int MODE>
__global__ __launch_bounds__(256, 2) void conv_tl(
    const u16* __restrict__ in, const u16* __restrict__ wrp,
    const float* __restrict__ bias, u16* __restrict__ out,
    const int* __restrict__ boxes, const int* __restrict__ wl, int wbase) {
  constexpr int BM = 128, BN = 128, BK = 64, TAPS = 9;
  constexpr int KB = CIN / BK;
  constexpr int KS = TAPS * KB;
  constexpr int NT = 256;
  constexpr int COUT = 256;
  constexpr int ACH = 4, AH = 2, BH = 2, HALF = 4;
  constexpr int ASZ = BM * BK;
  constexpr int BSZ = BN * BK;
  constexpr int TSLOT = (MODE == 0) ? 400 : (MODE == 1) ? 324 : 256;
  constexpr int TIN_SLOT = (MODE == 1) ? 400 : (MODE == 2) ? 324 : 0;
  __shared__ u16 smem[2 * (ASZ + BSZ)];  // 64 KB

  const int item = wl[wbase + blockIdx.x];
  if (item < 0) return;
  const int box = item >> 6;
  const int c0 = (item >> 1) & 31;
  const int cb = item & 1;
  const int* bx = boxes + box * 4;
  const int a = box / 50;
  const int bw = bx[1] - bx[0], bh = bx[3] - bx[2];
  const int bwO = bw + 2 * EOUT, bhO = bh + 2 * EOUT;  // output extent
  const int NPX = bwO * bhO;
  const int org_r = bx[2] - EOUT, org_c = bx[0] - EOUT;
  const int bwIn = bw + 2 * (EOUT + 1);               // input tile width

  const int tid = threadIdx.x;
  const int lane = tid & 63;
  const int wid = tid >> 6;
  const int wr = wid >> 1;
  const int wc = wid & 1;

  const u16* src = (MODE == 0) ? in : in + (size_t)box * TIN_SLOT * CIN;

  int aoff[ACH];
#pragma unroll
  for (int i = 0; i < ACH; ++i) {
    int c = tid + i * NT;
    int p = c >> 3, u = c & 7;
    int lu = u ^ (p & 7);
    int idx = c0 * 128 + p;
    if (idx >= NPX) idx = NPX - 1;
    int r = idx / bwO, cc = idx - r * bwO;
    if (MODE == 0) {
      int mr = org_r + r, mc = org_c + cc;
      mr = min(max(mr, 0), H - 1);
      mc = min(max(mc, 0), W - 1);
      aoff[i] = ((a * HP + mr + 1) * WP + (mc + 1)) * CIN + lu * 8;
    } else {
      // input tile org is output org - 1: offset (+1,+1) into input tile
      aoff[i] = ((r + 1) * bwIn + (cc + 1)) * CIN + lu * 8;
    }
  }

  f32x4 acc[4][4];
#pragma unroll
  for (int m = 0; m < 4; ++m)
#pragma unroll
    for (int n = 0; n < 4; ++n) acc[m][n] = f32x4{0.f, 0.f, 0.f, 0.f};

  const int g = lane >> 4;
  const int arow = lane & 15;
  const int fk = arow & 7;
  const int stride = (MODE == 0) ? WP : bwIn;

  auto stage = [&](int s, int h) {
    int par = s & 1;
    u16* Ad = smem + par * ASZ;
    u16* Bd = smem + 2 * ASZ + par * BSZ;
    int t = s / KB;
    int kb = s - t * KB;
    int doff = kb * BK + ((t / 3 - 1) * stride + (t % 3 - 1)) * CIN;
    const u16* wtile = wrp + (size_t)s * (COUT * BK) + cb * BSZ;
#pragma unroll
    for (int i = h * AH; i < h * AH + AH; ++i)
      gload16(src + aoff[i] + doff, Ad + (tid + i * NT) * 8);
#pragma unroll
    for (int i = h * BH; i < h * BH + BH; ++i)
      gload16(wtile + (tid + i * NT) * 8, Bd + (tid + i * NT) * 8);
  };

  stage(0, 0);
  stage(0, 1);

  for (int s = 0; s < KS; ++s) {
    int par = s & 1;
    const u16* Ab = smem + par * ASZ;
    const u16* Bb = smem + 2 * ASZ + par * BSZ;
    if (s + 1 < KS) {
      stage(s + 1, 0);
      waitcnt_vm<HALF>();
    } else {
      waitcnt_vm<0>();
    }
    __builtin_amdgcn_s_barrier();

#pragma unroll
    for (int j = 0; j < 2; ++j) {
      bf16x8 af[4], bfr[4];
#pragma unroll
      for (int m = 0; m < 4; ++m)
        af[m] = *reinterpret_cast<const bf16x8*>(
            Ab + (wr * 64 + m * 16 + arow) * 64 + (((j * 4 + g) ^ fk) << 3));
#pragma unroll
      for (int n = 0; n < 4; ++n)
        bfr[n] = *reinterpret_cast<const bf16x8*>(
            Bb + (wc * 64 + n * 16 + arow) * 64 + (((j * 4 + g) ^ fk) << 3));
      __builtin_amdgcn_s_setprio(1);
#pragma unroll
      for (int m = 0; m < 4; ++m)
#pragma unroll
        for (int n = 0; n < 4; ++n)
          acc[m][n] = __builtin_amdgcn_mfma_f32_16x16x32_bf16(af[m], bfr[n], acc[m][n], 0, 0, 0);
      __builtin_amdgcn_s_setprio(0);
      if (j == 0 && s + 1 < KS) stage(s + 1, 1);
    }
    __builtin_amdgcn_s_barrier();
  }

  __syncthreads();
  float bs[4];
#pragma unroll
  for (int n = 0; n < 4; ++n) bs[n] = bias[chlog(cb * BN + wc * 64 + n * 16 + arow)];
  u16* et = smem + wid * 2048;
#pragma unroll
  for (int pp = 0; pp < 2; ++pp) {
    if (pp) __syncthreads();
#pragma unroll
    for (int mm = 0; mm < 2; ++mm) {
      int m = pp * 2 + mm;
#pragma unroll
      for (int rg = 0; rg < 4; ++rg) {
        int row = mm * 16 + g * 4 + rg;
#pragma unroll
        for (int n = 0; n < 4; ++n) {
          int col = (n * 16 + arow) ^ (g << 4);
          et[row * 64 + col] = f2bf(fmaxf(acc[m][n][rg] + bs[n], 0.f));
        }
      }
    }
    __syncthreads();
#pragma unroll
    for (int jj = 0; jj < 4; ++jj) {
      int p = jj * 8 + (lane >> 3);
      int un = lane & 7;
      int su = un ^ (((p >> 2) & 3) << 1);
      uint4 qv = *reinterpret_cast<const uint4*>(et + p * 64 + su * 8);
      int idx = c0 * 128 + wr * 64 + pp * 32 + p;
      if (idx >= NPX) idx = NPX - 1;  // dup writes, same value
      if (MODE != 2) {
        int r2 = idx / bwO, c2 = idx - (idx / bwO) * bwO;
        int mr = org_r + r2, mc = org_c + c2;
        if (mr < 0 || mr >= H || mc < 0 || mc >= W)
          qv = make_uint4(0u, 0u, 0u, 0u);  // reference zero padding
      }
      size_t ob = ((size_t)box * TSLOT + idx) * COUT + cb * BN + wc * 64 + un * 8;
      *reinterpret_cast<uint4*>(out + ob) = qv;
    }
  }
}

// ---------------------------------------------------------------------------
// Fused Db(1x1)+relu -> F(1x1)+relu -> box-mean, reading T2 compact tiles.
__global__ __launch_bounds__(256) void fuse_box(
    const u16* __restrict__ x, const u16* __restrict__ wDbp,
    const float* __restrict__ bDb, const u16* __restrict__ wFp,
    const float* __restrict__ bF, const int* __restrict__ boxes,
    float* __restrict__ desc) {
  __shared__ u16 xT[16 * 256];  // 8 KB
  const int blk = blockIdx.x;   // slice-local box index
  const int* bx = boxes + blk * 4;
  const int bw = bx[1] - bx[0];
  const int npx = bw * (bx[3] - bx[2]);
  const int nch = (npx + 15) >> 4;
  const int tid = threadIdx.x;
  const int lane = tid & 63;
  const int wc = tid >> 6;
  const int g = lane >> 4;
  const int arow = lane & 15;

  float b1[4], b2[4];
#pragma unroll
  for (int nf = 0; nf < 4; ++nf) {
    int ch = wc * 64 + nf * 16 + arow;
    b1[nf] = bDb[chlog(ch)];
    b2[nf] = bF[chlog(ch)];
  }
  float sums[4] = {0.f, 0.f, 0.f, 0.f};

  for (int ci = 0; ci < nch; ++ci) {
    int idx = ci * 16 + arow;
    if (idx >= npx) idx = npx - 1;
    const u16* ap = x + ((size_t)blk * 256 + idx) * 256;  // T2 contiguous
    f32x4 a1[4];
#pragma unroll
    for (int nf = 0; nf < 4; ++nf) a1[nf] = f32x4{0.f, 0.f, 0.f, 0.f};
#pragma unroll
    for (int kb = 0; kb < 8; ++kb) {
      bf16x8 af = *reinterpret_cast<const bf16x8*>(ap + kb * 32 + g * 8);
#pragma unroll
      for (int nf = 0; nf < 4; ++nf) {
        bf16x8 bf_ = *reinterpret_cast<const bf16x8*>(
            wDbp + (((size_t)kb * 256 + wc * 64 + nf * 16 + arow) * 4 + g) * 8);
        a1[nf] = __builtin_amdgcn_mfma_f32_16x16x32_bf16(af, bf_, a1[nf], 0, 0, 0);
      }
    }
    if (ci) __syncthreads();
#pragma unroll
    for (int nf = 0; nf < 4; ++nf)
#pragma unroll
      for (int rg = 0; rg < 4; ++rg) {
        int px = g * 4 + rg;
        int ch = wc * 64 + nf * 16 + arow;
        int siu = (ch >> 3) ^ (px & 7);
        xT[px * 256 + siu * 8 + (ch & 7)] = f2bf(fmaxf(a1[nf][rg] + b1[nf], 0.f));
      }
    __syncthreads();
    f32x4 a2[4];
#pragma unroll
    for (int nf = 0; nf < 4; ++nf) a2[nf] = f32x4{0.f, 0.f, 0.f, 0.f};
#pragma unroll
    for (int kb = 0; kb < 8; ++kb) {
      int iu = kb * 4 + g;
      bf16x8 af2 = *reinterpret_cast<const bf16x8*>(
          xT + arow * 256 + (iu ^ (arow & 7)) * 8);
#pragma unroll
      for (int nf = 0; nf < 4; ++nf) {
        bf16x8 bf_ = *reinterpret_cast<const bf16x8*>(
            wFp + (((size_t)kb * 256 + wc * 64 + nf * 16 + arow) * 4 + g) * 8);
        a2[nf] = __builtin_amdgcn_mfma_f32_16x16x32_bf16(af2, bf_, a2[nf], 0, 0, 0);
      }
    }
#pragma unroll
    for (int nf = 0; nf < 4; ++nf)
#pragma unroll
      for (int rg = 0; rg < 4; ++rg) {
        int pidx = ci * 16 + g * 4 + rg;
        if (pidx < npx) sums[nf] += fmaxf(a2[nf][rg] + b2[nf], 0.f);
      }
  }
#pragma unroll
  for (int nf = 0; nf < 4; ++nf) {
    sums[nf] += __shfl_xor(sums[nf], 16, 64);
    sums[nf] += __shfl_xor(sums[nf], 32, 64);
  }
  if (g == 0) {
    float inv = 1.f / (float)npx;
#pragma unroll
    for (int nf = 0; nf < 4; ++nf) {
      int ch = wc * 64 + nf * 16 + arow;
      desc[(size_t)blk * 256 + chlog(ch)] = sums[nf] * inv;
    }
  }
}

// ---------------------------------------------------------------------------
extern "C" void kernel_launch(void* const* d_in, const int* in_sizes, int n_in,
                              void* d_out, int out_size, void* d_ws, size_t ws_size,
                              hipStream_t stream) {
  const float* feature = (const float*)d_in[0];
  const int* boxes = (const int*)d_in[1];
  const float* w1a = (const float*)d_in[2];
  const float* b1a = (const float*)d_in[3];
  const float* w1b = (const float*)d_in[4];
  const float* b1b = (const float*)d_in[5];
  const float* w2a = (const float*)d_in[6];
  const float* b2a = (const float*)d_in[7];
  const float* w2b = (const float*)d_in[8];
  const float* b2b = (const float*)d_in[9];
  const float* w3a = (const float*)d_in[10];
  const float* b3a = (const float*)d_in[11];
  const float* w3b = (const float*)d_in[12];
  const float* b3b = (const float*)d_in[13];
  const float* wDa = (const float*)d_in[14];
  const float* bDa = (const float*)d_in[15];
  const float* wDb = (const float*)d_in[16];
  const float* bDb = (const float*)d_in[17];
  const float* wF = (const float*)d_in[18];
  const float* bF = (const float*)d_in[19];

  const size_t e1a = (size_t)9 * 64 * 128;
  const size_t e128 = (size_t)9 * 128 * 128;
  const size_t e3a = (size_t)9 * 128 * 256;
  const size_t e256 = (size_t)9 * 256 * 256;
  const size_t ePl = (size_t)256 * 256;
  const size_t WELEMS = e1a + 3 * e128 + e3a + 2 * e256 + 2 * ePl;
  const size_t WB = WELEMS * 2 + (size_t)512 * 48 * 4;  // + worklists
  // Arena per agent: RA = 192ch full-map (in64+X, later T0/T2 tiles),
  // RB = 128ch full-map (Y, later T1 tiles). 320ch total = 23.1 MB/agent.
  const size_t PER_A = (size_t)320 * HP * WP * 2;
  int aloc = (ws_size >= 8 * PER_A + WB) ? 8 : (ws_size >= 4 * PER_A + WB) ? 4 : 2;

  char* ws = (char*)d_ws;
  const size_t SZ64  = (size_t)aloc * HP * WP * 64 * 2;
  const size_t SZ128 = (size_t)aloc * HP * WP * 128 * 2;
  const size_t SZ192 = SZ64 + SZ128;
  u16* in64 = (u16*)(ws);             // RA
  u16* X    = (u16*)(ws + SZ64);      // RA
  u16* T0   = (u16*)(ws);             // RA alias (after 2b)
  u16* T2   = (u16*)(ws);             // RA alias (after 3b)
  u16* Y    = (u16*)(ws + SZ192);     // RB
  u16* T1   = (u16*)(ws + SZ192);     // RB alias (after 3a)
  u16* rp   = (u16*)(ws + SZ192 + SZ128);
  int* wl   = (int*)(ws + SZ192 + SZ128 + WELEMS * 2);

  const size_t o1a = 0;
  const size_t o1b = o1a + e1a;
  const size_t o2a = o1b + e128;
  const size_t o2b = o2a + e128;
  const size_t o3a = o2b + e128;
  const size_t o3b = o3a + e3a;
  const size_t oDa = o3b + e256;
  const size_t oDbP = oDa + e256;
  const size_t oFP = oDbP + ePl;

  auto rpk = [&](const float* wsrc, size_t off, int O, int I, int taps) {
    int total = O * I * taps;
    repack_w<<<(total + 255) / 256, 256, 0, stream>>>(wsrc, rp + off, O, I, taps);
  };
  rpk(w1a, o1a, 128, 64, 9);
  rpk(w1b, o1b, 128, 128, 9);
  rpk(w2a, o2a, 128, 128, 9);
  rpk(w2b, o2b, 128, 128, 9);
  rpk(w3a, o3a, 256, 128, 9);
  rpk(w3b, o3b, 256, 256, 9);
  rpk(wDa, oDa, 256, 256, 9);
  repack_plain<<<256, 256, 0, stream>>>(wDb, rp + oDbP);
  repack_plain<<<256, 256, 0, stream>>>(wF, rp + oFP);

  const int nbox = aloc * 50;
  const int nbox8 = (nbox + 7) & ~7;
  // worklist bases (layers 0..6: 1a,1b,2a,2b,3a,3b,Da); NC=2 for tail layers
  int wb0 = 0;
  int wb1 = wb0 + nbox8 * 7;
  int wb2 = wb1 + nbox8 * 6;
  int wb3 = wb2 + nbox8 * 5;
  int wb4 = wb3 + nbox8 * 4;
  int wb5 = wb4 + nbox8 * 8;
  int wb6 = wb5 + nbox8 * 6;

  for (int a0 = 0; a0 < AG; a0 += aloc) {
    const int* bxs = boxes + (size_t)a0 * 50 * 4;
    build_wl<<<1, 512, 0, stream>>>(bxs, nbox, wl);
    // RA/RB bytes (incl. borders) were corrupted by previous tile writes
    zero_border<64><<<(aloc * NB * 8 + 255) / 256, 256, 0, stream>>>(in64, aloc);
    zero_border<128><<<(aloc * NB * 16 + 255) / 256, 256, 0, stream>>>(X, aloc);
    zero_border<128><<<(aloc * NB * 16 + 255) / 256, 256, 0, stream>>>(Y, aloc);

    convert_feat<<<aloc * H * 11, 256, 0, stream>>>(
        feature + (size_t)a0 * 64 * H * W, in64);

    // full-map box+halo chain (XCD-striped packed worklists)
    conv_boxk<64, 128, 7, 6><<<nbox8 * 7, 256, 0, stream>>>(in64, rp + o1a, b1a, X, bxs, wl, wb0);
    conv_boxk<128, 128, 6, 5><<<nbox8 * 6, 256, 0, stream>>>(X, rp + o1b, b1b, Y, bxs, wl, wb1);
    conv_boxk<128, 128, 5, 4><<<nbox8 * 5, 256, 0, stream>>>(Y, rp + o2a, b2a, X, bxs, wl, wb2);
    conv_boxk<128, 128, 4, 3><<<nbox8 * 4, 256, 0, stream>>>(X, rp + o2b, b2b, Y, bxs, wl, wb3);
    // variable-extent tile pipeline: 3a (Y -> T0), 3b (T0 -> T1), Da (T1 -> T2)
    conv_tl<128, 2, 4, 0><<<nbox8 * 8, 256, 0, stream>>>(Y, rp + o3a, b3a, T0, bxs, wl, wb4);
    conv_tl<256, 1, 3, 1><<<nbox8 * 6, 256, 0, stream>>>(T0, rp + o3b, b3b, T1, bxs, wl, wb5);
    conv_tl<256, 0, 2, 2><<<nbox8 * 4, 256, 0, stream>>>(T1, rp + oDa, bDa, T2, bxs, wl, wb6);
    // fused Db+relu -> F+relu -> box-mean
    fuse_box<<<nbox, 256, 0, stream>>>(
        T2, rp + oDbP, bDb, rp + oFP, bF, bxs,
        ((float*)d_out) + (size_t)a0 * 50 * 256);
  }
}

// Round 21
// 604.273 us; speedup vs baseline: 1.0167x; 1.0167x over previous
//
#include <hip/hip_runtime.h>
#include <hip/hip_bf16.h>

typedef unsigned int u32;
typedef unsigned short u16;
typedef __attribute__((ext_vector_type(8))) short bf16x8;   // 8 bf16 = 4 VGPRs
typedef __attribute__((ext_vector_type(4))) float f32x4;

#define DEVI __device__ __forceinline__

constexpr int AG = 8, H = 100, W = 352, HP = 102, WP = 354;
constexpr int HWp = H * W;          // 35200
constexpr int NB = 2 * WP + 2 * H;  // 908 border pixels per agent

DEVI u16 f2bf(float f) {
  __hip_bfloat16 h = __float2bfloat16(f);
  return *reinterpret_cast<u16*>(&h);
}
DEVI float bf2f(u16 v) { return __uint_as_float(((u32)v) << 16); }

// interleaved channel order within each 32-block: stored 8v+j <-> logical
// {4v+j (j<4), 16+4v+(j-4) (j>=4)} so one 16B unit = one MFMA k-fragment.
DEVI int chperm(int j) { int v = j >> 3, r = j & 7; return (r < 4) ? 4 * v + r : 16 + 4 * v + (r - 4); }
DEVI int chlog(int c) { return (c & ~31) + chperm(c & 31); }

typedef __attribute__((address_space(1))) const u32 as1c_u32;
typedef __attribute__((address_space(3))) u32 as3_u32;
DEVI void gload16(const u16* g, u16* l) {
  __builtin_amdgcn_global_load_lds((as1c_u32*)(const void*)g, (as3_u32*)(void*)l, 16, 0, 0);
}

template <int N> DEVI void waitcnt_vm() {
  if constexpr (N == 0) asm volatile("s_waitcnt vmcnt(0)" ::: "memory");
  else if constexpr (N == 3) asm volatile("s_waitcnt vmcnt(3)" ::: "memory");
  else if constexpr (N == 4) asm volatile("s_waitcnt vmcnt(4)" ::: "memory");
  else asm volatile("s_waitcnt vmcnt(0)" ::: "memory");
}

// ---------------------------------------------------------------------------
// Packed worklists: per conv layer, the exact non-empty (box,chunk) items,
// padded with -1 to nbox*MAXCH. Real items sit at the FRONT; conv kernels use
// raw blockIdx (hardware round-robins consecutive ids across the 8 XCDs), so
// packed work is automatically XCD-balanced. Layer geometry MUST match:
//   L0..L3 (conv_boxk 1a,1b,2a,2b): npx = clamp(box+HALO), HALO=6,5,4,3
//   L4 (3a): (bw+4)*(bh+4); L5 (3b): (bw+2)*(bh+2); L6 (Da): bw*bh
constexpr int WL_MAXCH[7] = {7, 6, 5, 4, 4, 3, 2};
__global__ void build_wl(const int* __restrict__ boxes, int nbox,
                         int* __restrict__ wl) {
  __shared__ int cnt[7][512];
  __shared__ int base_l[8];
  int t = threadIdx.x;
  if (t == 0) {
    int b = 0;
    for (int l = 0; l < 7; ++l) { base_l[l] = b; b += nbox * WL_MAXCH[l]; }
    base_l[7] = b;
  }
  __syncthreads();
  int total = base_l[7];
  for (int i = t; i < total; i += 512) wl[i] = -1;  // pad
  if (t < nbox) {
    const int* bx = boxes + t * 4;
    int bw = bx[1] - bx[0], bh = bx[3] - bx[2];
#pragma unroll
    for (int l = 0; l < 4; ++l) {
      int halo = 6 - l;
      int cl = max(bx[0] - halo, 0), cr = min(bx[1] + halo, W);
      int r0 = max(bx[2] - halo, 0), r1 = min(bx[3] + halo, H);
      cnt[l][t] = min(((cr - cl) * (r1 - r0) + 127) >> 7, WL_MAXCH[l]);
    }
    cnt[4][t] = min(((bw + 4) * (bh + 4) + 127) >> 7, 4);
    cnt[5][t] = min(((bw + 2) * (bh + 2) + 127) >> 7, 3);
    cnt[6][t] = min((bw * bh + 127) >> 7, 2);
  }
  __syncthreads();
  if (t == 0) {  // deterministic exclusive scan, in place (counts -> offsets)
    for (int l = 0; l < 7; ++l) {
      int run = 0;
      for (int b = 0; b < nbox; ++b) {
        int c = cnt[l][b];
        cnt[l][b] = run;
        run += c;
      }
    }
  }
  __syncthreads();
  if (t < nbox) {
    const int* bx = boxes + t * 4;
    int bw = bx[1] - bx[0], bh = bx[3] - bx[2];
    int nc[7];
#pragma unroll
    for (int l = 0; l < 4; ++l) {
      int halo = 6 - l;
      int cl = max(bx[0] - halo, 0), cr = min(bx[1] + halo, W);
      int r0 = max(bx[2] - halo, 0), r1 = min(bx[3] + halo, H);
      nc[l] = min(((cr - cl) * (r1 - r0) + 127) >> 7, WL_MAXCH[l]);
    }
    nc[4] = min(((bw + 4) * (bh + 4) + 127) >> 7, 4);
    nc[5] = min(((bw + 2) * (bh + 2) + 127) >> 7, 3);
    nc[6] = min((bw * bh + 127) >> 7, 2);
#pragma unroll
    for (int l = 0; l < 7; ++l)
      for (int c = 0; c < nc[l]; ++c)
        wl[base_l[l] + cnt[l][t] + c] = (t << 4) | c;
  }
}

// ---------------------------------------------------------------------------
// feature slice fp32 NCHW -> padded NHWC(permuted) bf16 interior, via LDS
// transpose. grid: aloc*H*11 blocks; block 256 thr.
__global__ void convert_feat(const float* __restrict__ f, u16* __restrict__ dst) {
  __shared__ float t32[64][33];
  int blk = blockIdx.x;
  int wseg = blk % 11;
  int rest = blk / 11;
  int h = rest % H;
  int a = rest / H;
  int t = threadIdx.x;
  int wbase = wseg * 32;
  {
    int w = t & 31;
    int c0 = (t >> 5) * 8;
#pragma unroll
    for (int i = 0; i < 8; ++i) {
      int lc = c0 + i;
      t32[lc][w] = f[((size_t)(a * 64 + lc) * H + h) * W + wbase + w];
    }
  }
  __syncthreads();
  int p = t >> 3;
  int cs = (t & 7) * 8;
  u16 tmp[8];
#pragma unroll
  for (int j = 0; j < 8; ++j) {
    int c = cs + j;
    int lc = (c & 32) + chperm(c & 31);
    tmp[j] = f2bf(t32[lc][p]);
  }
  size_t ob = ((size_t)(a * HP + h + 1) * WP + (wbase + p + 1)) * 64 + cs;
  *reinterpret_cast<uint4*>(dst + ob) = *reinterpret_cast<uint4*>(tmp);
}

// zero the 1-pixel border of a padded NHWC buffer with C channels, nA agents
template <int C>
__global__ void zero_border(u16* __restrict__ buf, int nA) {
  constexpr int CH = C / 8;
  int idx = blockIdx.x * 256 + threadIdx.x;
  int pix = idx / CH;
  int cc = (idx - pix * CH) * 8;
  if (pix >= nA * NB) return;
  int a = pix / NB;
  int b = pix - a * NB;
  int h, w;
  if (b < WP) { h = 0; w = b; }
  else if (b < 2 * WP) { h = HP - 1; w = b - WP; }
  else {
    int bb = b - 2 * WP;
    int bb2 = (bb < H) ? bb : bb - H;
    h = 1 + bb2;
    w = (bb < H) ? 0 : (WP - 1);
  }
  size_t off = ((size_t)(a * HP + h) * WP + w) * C + cc;
  *reinterpret_cast<uint4*>(buf + off) = make_uint4(0u, 0u, 0u, 0u);
}

// w [O][I][kh][kw] fp32 -> rp[s=t*KB+kb][r:O][u:8][jj:8] bf16 with the LDS
// row-XOR swizzle baked in: stored (r,u) holds logical unit lu = u^(r&7).
__global__ void repack_w(const float* __restrict__ w, u16* __restrict__ rp,
                         int O, int I, int taps) {
  int idx = blockIdx.x * 256 + threadIdx.x;
  int total = O * I * taps;
  if (idx >= total) return;
  int jj = idx & 7;
  int u = (idx >> 3) & 7;
  int r = (idx >> 6) % O;
  int s = idx / (O * 64);
  int KB = I >> 6;
  int kb = s % KB;
  int t = s / KB;
  int lu = u ^ (r & 7);
  int g = lu & 3, j32 = lu >> 2;
  int cp = (jj < 4) ? 4 * g + jj : 16 + 4 * g + (jj - 4);
  int i = kb * 64 + j32 * 32 + cp;
  int o = (r & ~31) + chperm(r & 31);
  rp[idx] = f2bf(w[((size_t)o * I + i) * taps + t]);
}

// 1x1 weight [256][256] fp32 -> plain rp[kb32:8][r:256][g:4][jj:8]
__global__ void repack_plain(const float* __restrict__ w, u16* __restrict__ rp) {
  int idx = blockIdx.x * 256 + threadIdx.x;  // 65536 total
  int jj = idx & 7;
  int g = (idx >> 3) & 3;
  int r = (idx >> 5) & 255;
  int kb = idx >> 13;
  int cp = (jj < 4) ? 4 * g + jj : 16 + 4 * g + (jj - 4);
  int i = kb * 32 + cp;
  int o = chlog(r);
  rp[idx] = f2bf(w[(size_t)o * 256 + i]);
}

// ---------------------------------------------------------------------------
// Box-restricted 3x3 conv on full padded maps (round-16 proven config):
// BK=64, 64KB dbuf LDS, half-split staging, counted vmcnt, setprio.
// Worklist items via RAW blockIdx (round-robin XCD balance of packed work).
template <int CIN, int COUT, int MAXCH, int HALO>
__global__ __launch_bounds__(256, 2) void conv_boxk(
    const u16* __restrict__ in, const u16* __restrict__ wrp,
    const float* __restrict__ bias, u16* __restrict__ out,
    const int* __restrict__ boxes, const int* __restrict__ wl, int wbase) {
  constexpr int BM = 128, BN = 128, BK = 64, TAPS = 9;
  constexpr int KB = CIN / BK;
  constexpr int KS = TAPS * KB;
  constexpr int NT = 256;
  constexpr int NC = COUT / BN;
  constexpr int ACH = 4, AH = 2, BH = 2, HALF = 4;
  constexpr int ASZ = BM * BK;
  constexpr int BSZ = BN * BK;
  __shared__ u16 smem[2 * (ASZ + BSZ)];  // 64 KB

  const int blk = blockIdx.x;
  const int cb = blk % NC;
  const int item = wl[wbase + blk / NC];
  if (item < 0) return;
  const int box = item >> 4;
  const int c0 = item & 15;
  const int* bx = boxes + box * 4;
  const int a = box / 50;
  const int cl = max(bx[0] - HALO, 0);
  const int cr = min(bx[1] + HALO, W);
  const int r0 = max(bx[2] - HALO, 0);
  const int r1 = min(bx[3] + HALO, H);
  const int bw = cr - cl;
  const int npx = bw * (r1 - r0);

  const int tid = threadIdx.x;
  const int lane = tid & 63;
  const int wid = tid >> 6;
  const int wr = wid >> 1;
  const int wc = wid & 1;

  int aoff[ACH];
#pragma unroll
  for (int i = 0; i < ACH; ++i) {
    int c = tid + i * NT;
    int p = c >> 3, u = c & 7;
    int lu = u ^ (p & 7);
    int idx = c0 * 128 + p;
    if (idx >= npx) idx = npx - 1;
    int ph = r0 + idx / bw;
    int pw = cl + idx % bw;
    aoff[i] = ((a * HP + ph + 1) * WP + (pw + 1)) * CIN + lu * 8;
  }

  f32x4 acc[4][4];
#pragma unroll
  for (int m = 0; m < 4; ++m)
#pragma unroll
    for (int n = 0; n < 4; ++n) acc[m][n] = f32x4{0.f, 0.f, 0.f, 0.f};

  const int g = lane >> 4;
  const int arow = lane & 15;
  const int fk = arow & 7;

  auto stage = [&](int s, int h) {
    int par = s & 1;
    u16* Ad = smem + par * ASZ;
    u16* Bd = smem + 2 * ASZ + par * BSZ;
    int t = s / KB;
    int kb = s - t * KB;
    int doff = kb * BK + ((t / 3 - 1) * WP + (t % 3 - 1)) * CIN;
    const u16* wtile = wrp + (size_t)s * (COUT * BK) + cb * BSZ;
#pragma unroll
    for (int i = h * AH; i < h * AH + AH; ++i)
      gload16(in + aoff[i] + doff, Ad + (tid + i * NT) * 8);
#pragma unroll
    for (int i = h * BH; i < h * BH + BH; ++i)
      gload16(wtile + (tid + i * NT) * 8, Bd + (tid + i * NT) * 8);
  };

  stage(0, 0);
  stage(0, 1);

  for (int s = 0; s < KS; ++s) {
    int par = s & 1;
    const u16* Ab = smem + par * ASZ;
    const u16* Bb = smem + 2 * ASZ + par * BSZ;
    if (s + 1 < KS) {
      stage(s + 1, 0);
      waitcnt_vm<HALF>();
    } else {
      waitcnt_vm<0>();
    }
    __builtin_amdgcn_s_barrier();

#pragma unroll
    for (int j = 0; j < 2; ++j) {
      bf16x8 af[4], bfr[4];
#pragma unroll
      for (int m = 0; m < 4; ++m)
        af[m] = *reinterpret_cast<const bf16x8*>(
            Ab + (wr * 64 + m * 16 + arow) * 64 + (((j * 4 + g) ^ fk) << 3));
#pragma unroll
      for (int n = 0; n < 4; ++n)
        bfr[n] = *reinterpret_cast<const bf16x8*>(
            Bb + (wc * 64 + n * 16 + arow) * 64 + (((j * 4 + g) ^ fk) << 3));
      __builtin_amdgcn_s_setprio(1);
#pragma unroll
      for (int m = 0; m < 4; ++m)
#pragma unroll
        for (int n = 0; n < 4; ++n)
          acc[m][n] = __builtin_amdgcn_mfma_f32_16x16x32_bf16(af[m], bfr[n], acc[m][n], 0, 0, 0);
      __builtin_amdgcn_s_setprio(0);
      if (j == 0 && s + 1 < KS) stage(s + 1, 1);
    }
    __builtin_amdgcn_s_barrier();
  }

  __syncthreads();
  float bs[4];
#pragma unroll
  for (int n = 0; n < 4; ++n) bs[n] = bias[chlog(cb * BN + wc * 64 + n * 16 + arow)];
  u16* et = smem + wid * 2048;
#pragma unroll
  for (int pp = 0; pp < 2; ++pp) {
    if (pp) __syncthreads();
#pragma unroll
    for (int mm = 0; mm < 2; ++mm) {
      int m = pp * 2 + mm;
#pragma unroll
      for (int rg = 0; rg < 4; ++rg) {
        int row = mm * 16 + g * 4 + rg;
#pragma unroll
        for (int n = 0; n < 4; ++n) {
          int col = (n * 16 + arow) ^ (g << 4);
          et[row * 64 + col] = f2bf(fmaxf(acc[m][n][rg] + bs[n], 0.f));
        }
      }
    }
    __syncthreads();
#pragma unroll
    for (int jj = 0; jj < 4; ++jj) {
      int p = jj * 8 + (lane >> 3);
      int un = lane & 7;
      int su = un ^ (((p >> 2) & 3) << 1);
      uint4 qv = *reinterpret_cast<const uint4*>(et + p * 64 + su * 8);
      int idx = c0 * 128 + wr * 64 + pp * 32 + p;
      if (idx >= npx) idx = npx - 1;  // dup writes, same value
      int ph = r0 + idx / bw;
      int pw = cl + idx % bw;
      size_t ob = ((size_t)(a * HP + ph + 1) * WP + (pw + 1)) * COUT +
                  cb * BN + wc * 64 + un * 8;
      *reinterpret_cast<uint4*>(out + ob) = qv;
    }
  }
}

// ---------------------------------------------------------------------------
// Tile-pipeline conv for the tail (COUT=256, NC=2). Variable per-box extents,
// fixed slot strides (400/324/256). Round-16 dbuf pipeline + packed worklist
// via raw blockIdx.
template <int CIN, int EOUT, int MAXCH, int MODE>
__global__ __launch_bounds__(256, 2) void conv_tl(
    const u16* __restrict__ in, const u16* __restrict__ wrp,
    const float* __restrict__ bias, u16* __restrict__ out,
    const int* __restrict__ boxes, const int* __restrict__ wl, int wbase) {
  constexpr int BM = 128, BN = 128, BK = 64, TAPS = 9;
  constexpr int KB = CIN / BK;
  constexpr int KS = TAPS * KB;
  constexpr int NT = 256;
  constexpr int NC = 2;               // COUT = 256
  constexpr int COUT = 256;
  constexpr int ACH = 4, AH = 2, BH = 2, HALF = 4;
  constexpr int ASZ = BM * BK;
  constexpr int BSZ = BN * BK;
  constexpr int TSLOT = (MODE == 0) ? 400 : (MODE == 1) ? 324 : 256;
  constexpr int TIN_SLOT = (MODE == 1) ? 400 : (MODE == 2) ? 324 : 0;
  __shared__ u16 smem[2 * (ASZ + BSZ)];  // 64 KB

  const int blk = blockIdx.x;
  const int cb = blk % NC;
  const int item = wl[wbase + blk / NC];
  if (item < 0) return;
  const int box = item >> 4;
  const int c0 = item & 15;
  const int* bx = boxes + box * 4;
  const int a = box / 50;
  const int bw = bx[1] - bx[0], bh = bx[3] - bx[2];
  const int bwO = bw + 2 * EOUT, bhO = bh + 2 * EOUT;  // output extent
  const int NPX = bwO * bhO;
  const int org_r = bx[2] - EOUT, org_c = bx[0] - EOUT;
  const int bwIn = bw + 2 * (EOUT + 1);               // input tile width

  const int tid = threadIdx.x;
  const int lane = tid & 63;
  const int wid = tid >> 6;
  const int wr = wid >> 1;
  const int wc = wid & 1;

  const u16* src = (MODE == 0) ? in : in + (size_t)box * TIN_SLOT * CIN;

  int aoff[ACH];
#pragma unroll
  for (int i = 0; i < ACH; ++i) {
    int c = tid + i * NT;
    int p = c >> 3, u = c & 7;
    int lu = u ^ (p & 7);
    int idx = c0 * 128 + p;
    if (idx >= NPX) idx = NPX - 1;
    int r = idx / bwO, cc = idx - r * bwO;
    if (MODE == 0) {
      int mr = org_r + r, mc = org_c + cc;
      mr = min(max(mr, 0), H - 1);
      mc = min(max(mc, 0), W - 1);
      aoff[i] = ((a * HP + mr + 1) * WP + (mc + 1)) * CIN + lu * 8;
    } else {
      // input tile org is output org - 1: offset (+1,+1) into input tile
      aoff[i] = ((r + 1) * bwIn + (cc + 1)) * CIN + lu * 8;
    }
  }

  f32x4 acc[4][4];
#pragma unroll
  for (int m = 0; m < 4; ++m)
#pragma unroll
    for (int n = 0; n < 4; ++n) acc[m][n] = f32x4{0.f, 0.f, 0.f, 0.f};

  const int g = lane >> 4;
  const int arow = lane & 15;
  const int fk = arow & 7;
  const int stride = (MODE == 0) ? WP : bwIn;

  auto stage = [&](int s, int h) {
    int par = s & 1;
    u16* Ad = smem + par * ASZ;
    u16* Bd = smem + 2 * ASZ + par * BSZ;
    int t = s / KB;
    int kb = s - t * KB;
    int doff = kb * BK + ((t / 3 - 1) * stride + (t % 3 - 1)) * CIN;
    const u16* wtile = wrp + (size_t)s * (COUT * BK) + cb * BSZ;
#pragma unroll
    for (int i = h * AH; i < h * AH + AH; ++i)
      gload16(src + aoff[i] + doff, Ad + (tid + i * NT) * 8);
#pragma unroll
    for (int i = h * BH; i < h * BH + BH; ++i)
      gload16(wtile + (tid + i * NT) * 8, Bd + (tid + i * NT) * 8);
  };

  stage(0, 0);
  stage(0, 1);

  for (int s = 0; s < KS; ++s) {
    int par = s & 1;
    const u16* Ab = smem + par * ASZ;
    const u16* Bb = smem + 2 * ASZ + par * BSZ;
    if (s + 1 < KS) {
      stage(s + 1, 0);
      waitcnt_vm<HALF>();
    } else {
      waitcnt_vm<0>();
    }
    __builtin_amdgcn_s_barrier();

#pragma unroll
    for (int j = 0; j < 2; ++j) {
      bf16x8 af[4], bfr[4];
#pragma unroll
      for (int m = 0; m < 4; ++m)
        af[m] = *reinterpret_cast<const bf16x8*>(
            Ab + (wr * 64 + m * 16 + arow) * 64 + (((j * 4 + g) ^ fk) << 3));
#pragma unroll
      for (int n = 0; n < 4; ++n)
        bfr[n] = *reinterpret_cast<const bf16x8*>(
            Bb + (wc * 64 + n * 16 + arow) * 64 + (((j * 4 + g) ^ fk) << 3));
      __builtin_amdgcn_s_setprio(1);
#pragma unroll
      for (int m = 0; m < 4; ++m)
#pragma unroll
        for (int n = 0; n < 4; ++n)
          acc[m][n] = __builtin_amdgcn_mfma_f32_16x16x32_bf16(af[m], bfr[n], acc[m][n], 0, 0, 0);
      __builtin_amdgcn_s_setprio(0);
      if (j == 0 && s + 1 < KS) stage(s + 1, 1);
    }
    __builtin_amdgcn_s_barrier();
  }

  __syncthreads();
  float bs[4];
#pragma unroll
  for (int n = 0; n < 4; ++n) bs[n] = bias[chlog(cb * BN + wc * 64 + n * 16 + arow)];
  u16* et = smem + wid * 2048;
#pragma unroll
  for (int pp = 0; pp < 2; ++pp) {
    if (pp) __syncthreads();
#pragma unroll
    for (int mm = 0; mm < 2; ++mm) {
      int m = pp * 2 + mm;
#pragma unroll
      for (int rg = 0; rg < 4; ++rg) {
        int row = mm * 16 + g * 4 + rg;
#pragma unroll
        for (int n = 0; n < 4; ++n) {
          int col = (n * 16 + arow) ^ (g << 4);
          et[row * 64 + col] = f2bf(fmaxf(acc[m][n][rg] + bs[n], 0.f));
        }
      }
    }
    __syncthreads();
#pragma unroll
    for (int jj = 0; jj < 4; ++jj) {
      int p = jj * 8 + (lane >> 3);
      int un = lane & 7;
      int su = un ^ (((p >> 2) & 3) << 1);
      uint4 qv = *reinterpret_cast<const uint4*>(et + p * 64 + su * 8);
      int idx = c0 * 128 + wr * 64 + pp * 32 + p;
      if (idx >= NPX) idx = NPX - 1;  // dup writes, same value
      if (MODE != 2) {
        int r2 = idx / bwO, c2 = idx - (idx / bwO) * bwO;
        int mr = org_r + r2, mc = org_c + c2;
        if (mr < 0 || mr >= H || mc < 0 || mc >= W)
          qv = make_uint4(0u, 0u, 0u, 0u);  // reference zero padding
      }
      size_t ob = ((size_t)box * TSLOT + idx) * COUT + cb * BN + wc * 64 + un * 8;
      *reinterpret_cast<uint4*>(out + ob) = qv;
    }
  }
}

// ---------------------------------------------------------------------------
// Fused Db(1x1)+relu -> F(1x1)+relu -> box-mean, reading T2 compact tiles.
__global__ __launch_bounds__(256) void fuse_box(
    const u16* __restrict__ x, const u16* __restrict__ wDbp,
    const float* __restrict__ bDb, const u16* __restrict__ wFp,
    const float* __restrict__ bF, const int* __restrict__ boxes,
    float* __restrict__ desc) {
  __shared__ u16 xT[16 * 256];  // 8 KB
  const int blk = blockIdx.x;   // slice-local box index
  const int* bx = boxes + blk * 4;
  const int bw = bx[1] - bx[0];
  const int npx = bw * (bx[3] - bx[2]);
  const int nch = (npx + 15) >> 4;
  const int tid = threadIdx.x;
  const int lane = tid & 63;
  const int wc = tid >> 6;
  const int g = lane >> 4;
  const int arow = lane & 15;

  float b1[4], b2[4];
#pragma unroll
  for (int nf = 0; nf < 4; ++nf) {
    int ch = wc * 64 + nf * 16 + arow;
    b1[nf] = bDb[chlog(ch)];
    b2[nf] = bF[chlog(ch)];
  }
  float sums[4] = {0.f, 0.f, 0.f, 0.f};

  for (int ci = 0; ci < nch; ++ci) {
    int idx = ci * 16 + arow;
    if (idx >= npx) idx = npx - 1;
    const u16* ap = x + ((size_t)blk * 256 + idx) * 256;  // T2 contiguous
    f32x4 a1[4];
#pragma unroll
    for (int nf = 0; nf < 4; ++nf) a1[nf] = f32x4{0.f, 0.f, 0.f, 0.f};
#pragma unroll
    for (int kb = 0; kb < 8; ++kb) {
      bf16x8 af = *reinterpret_cast<const bf16x8*>(ap + kb * 32 + g * 8);
#pragma unroll
      for (int nf = 0; nf < 4; ++nf) {
        bf16x8 bf_ = *reinterpret_cast<const bf16x8*>(
            wDbp + (((size_t)kb * 256 + wc * 64 + nf * 16 + arow) * 4 + g) * 8);
        a1[nf] = __builtin_amdgcn_mfma_f32_16x16x32_bf16(af, bf_, a1[nf], 0, 0, 0);
      }
    }
    if (ci) __syncthreads();
#pragma unroll
    for (int nf = 0; nf < 4; ++nf)
#pragma unroll
      for (int rg = 0; rg < 4; ++rg) {
        int px = g * 4 + rg;
        int ch = wc * 64 + nf * 16 + arow;
        int siu = (ch >> 3) ^ (px & 7);
        xT[px * 256 + siu * 8 + (ch & 7)] = f2bf(fmaxf(a1[nf][rg] + b1[nf], 0.f));
      }
    __syncthreads();
    f32x4 a2[4];
#pragma unroll
    for (int nf = 0; nf < 4; ++nf) a2[nf] = f32x4{0.f, 0.f, 0.f, 0.f};
#pragma unroll
    for (int kb = 0; kb < 8; ++kb) {
      int iu = kb * 4 + g;
      bf16x8 af2 = *reinterpret_cast<const bf16x8*>(
          xT + arow * 256 + (iu ^ (arow & 7)) * 8);
#pragma unroll
      for (int nf = 0; nf < 4; ++nf) {
        bf16x8 bf_ = *reinterpret_cast<const bf16x8*>(
            wFp + (((size_t)kb * 256 + wc * 64 + nf * 16 + arow) * 4 + g) * 8);
        a2[nf] = __builtin_amdgcn_mfma_f32_16x16x32_bf16(af2, bf_, a2[nf], 0, 0, 0);
      }
    }
#pragma unroll
    for (int nf = 0; nf < 4; ++nf)
#pragma unroll
      for (int rg = 0; rg < 4; ++rg) {
        int pidx = ci * 16 + g * 4 + rg;
        if (pidx < npx) sums[nf] += fmaxf(a2[nf][rg] + b2[nf], 0.f);
      }
  }
#pragma unroll
  for (int nf = 0; nf < 4; ++nf) {
    sums[nf] += __shfl_xor(sums[nf], 16, 64);
    sums[nf] += __shfl_xor(sums[nf], 32, 64);
  }
  if (g == 0) {
    float inv = 1.f / (float)npx;
#pragma unroll
    for (int nf = 0; nf < 4; ++nf) {
      int ch = wc * 64 + nf * 16 + arow;
      desc[(size_t)blk * 256 + chlog(ch)] = sums[nf] * inv;
    }
  }
}

// ---------------------------------------------------------------------------
extern "C" void kernel_launch(void* const* d_in, const int* in_sizes, int n_in,
                              void* d_out, int out_size, void* d_ws, size_t ws_size,
                              hipStream_t stream) {
  const float* feature = (const float*)d_in[0];
  const int* boxes = (const int*)d_in[1];
  const float* w1a = (const float*)d_in[2];
  const float* b1a = (const float*)d_in[3];
  const float* w1b = (const float*)d_in[4];
  const float* b1b = (const float*)d_in[5];
  const float* w2a = (const float*)d_in[6];
  const float* b2a = (const float*)d_in[7];
  const float* w2b = (const float*)d_in[8];
  const float* b2b = (const float*)d_in[9];
  const float* w3a = (const float*)d_in[10];
  const float* b3a = (const float*)d_in[11];
  const float* w3b = (const float*)d_in[12];
  const float* b3b = (const float*)d_in[13];
  const float* wDa = (const float*)d_in[14];
  const float* bDa = (const float*)d_in[15];
  const float* wDb = (const float*)d_in[16];
  const float* bDb = (const float*)d_in[17];
  const float* wF = (const float*)d_in[18];
  const float* bF = (const float*)d_in[19];

  const size_t e1a = (size_t)9 * 64 * 128;
  const size_t e128 = (size_t)9 * 128 * 128;
  const size_t e3a = (size_t)9 * 128 * 256;
  const size_t e256 = (size_t)9 * 256 * 256;
  const size_t ePl = (size_t)256 * 256;
  const size_t WELEMS = e1a + 3 * e128 + e3a + 2 * e256 + 2 * ePl;
  const size_t WB = WELEMS * 2 + (size_t)512 * 31 * 4;  // + worklists
  // Arena per agent: RA = 192ch full-map (in64+X, later T0/T2 tiles),
  // RB = 128ch full-map (Y, later T1 tiles). 320ch total = 23.1 MB/agent.
  const size_t PER_A = (size_t)320 * HP * WP * 2;
  int aloc = (ws_size >= 8 * PER_A + WB) ? 8 : (ws_size >= 4 * PER_A + WB) ? 4 : 2;

  char* ws = (char*)d_ws;
  const size_t SZ64  = (size_t)aloc * HP * WP * 64 * 2;
  const size_t SZ128 = (size_t)aloc * HP * WP * 128 * 2;
  const size_t SZ192 = SZ64 + SZ128;
  u16* in64 = (u16*)(ws);             // RA
  u16* X    = (u16*)(ws + SZ64);      // RA
  u16* T0   = (u16*)(ws);             // RA alias (after 2b)
  u16* T2   = (u16*)(ws);             // RA alias (after 3b)
  u16* Y    = (u16*)(ws + SZ192);     // RB
  u16* T1   = (u16*)(ws + SZ192);     // RB alias (after 3a)
  u16* rp   = (u16*)(ws + SZ192 + SZ128);
  int* wl   = (int*)(ws + SZ192 + SZ128 + WELEMS * 2);

  const size_t o1a = 0;
  const size_t o1b = o1a + e1a;
  const size_t o2a = o1b + e128;
  const size_t o2b = o2a + e128;
  const size_t o3a = o2b + e128;
  const size_t o3b = o3a + e3a;
  const size_t oDa = o3b + e256;
  const size_t oDbP = oDa + e256;
  const size_t oFP = oDbP + ePl;

  auto rpk = [&](const float* wsrc, size_t off, int O, int I, int taps) {
    int total = O * I * taps;
    repack_w<<<(total + 255) / 256, 256, 0, stream>>>(wsrc, rp + off, O, I, taps);
  };
  rpk(w1a, o1a, 128, 64, 9);
  rpk(w1b, o1b, 128, 128, 9);
  rpk(w2a, o2a, 128, 128, 9);
  rpk(w2b, o2b, 128, 128, 9);
  rpk(w3a, o3a, 256, 128, 9);
  rpk(w3b, o3b, 256, 256, 9);
  rpk(wDa, oDa, 256, 256, 9);
  repack_plain<<<256, 256, 0, stream>>>(wDb, rp + oDbP);
  repack_plain<<<256, 256, 0, stream>>>(wF, rp + oFP);

  const int nbox = aloc * 50;
  // worklist bases (layers 0..6: 1a,1b,2a,2b,3a,3b,Da)
  int wb0 = 0;
  int wb1 = wb0 + nbox * 7;
  int wb2 = wb1 + nbox * 6;
  int wb3 = wb2 + nbox * 5;
  int wb4 = wb3 + nbox * 4;
  int wb5 = wb4 + nbox * 4;
  int wb6 = wb5 + nbox * 3;

  for (int a0 = 0; a0 < AG; a0 += aloc) {
    const int* bxs = boxes + (size_t)a0 * 50 * 4;
    build_wl<<<1, 512, 0, stream>>>(bxs, nbox, wl);
    // RA/RB bytes (incl. borders) were corrupted by previous tile writes
    zero_border<64><<<(aloc * NB * 8 + 255) / 256, 256, 0, stream>>>(in64, aloc);
    zero_border<128><<<(aloc * NB * 16 + 255) / 256, 256, 0, stream>>>(X, aloc);
    zero_border<128><<<(aloc * NB * 16 + 255) / 256, 256, 0, stream>>>(Y, aloc);

    convert_feat<<<aloc * H * 11, 256, 0, stream>>>(
        feature + (size_t)a0 * 64 * H * W, in64);

    // full-map box+halo chain (packed worklists, raw blockIdx)
    conv_boxk<64, 128, 7, 6><<<nbox * 7, 256, 0, stream>>>(in64, rp + o1a, b1a, X, bxs, wl, wb0);
    conv_boxk<128, 128, 6, 5><<<nbox * 6, 256, 0, stream>>>(X, rp + o1b, b1b, Y, bxs, wl, wb1);
    conv_boxk<128, 128, 5, 4><<<nbox * 5, 256, 0, stream>>>(Y, rp + o2a, b2a, X, bxs, wl, wb2);
    conv_boxk<128, 128, 4, 3><<<nbox * 4, 256, 0, stream>>>(X, rp + o2b, b2b, Y, bxs, wl, wb3);
    // variable-extent tile pipeline: 3a (Y -> T0), 3b (T0 -> T1), Da (T1 -> T2)
    conv_tl<128, 2, 4, 0><<<nbox * 4 * 2, 256, 0, stream>>>(Y, rp + o3a, b3a, T0, bxs, wl, wb4);
    conv_tl<256, 1, 3, 1><<<nbox * 3 * 2, 256, 0, stream>>>(T0, rp + o3b, b3b, T1, bxs, wl, wb5);
    conv_tl<256, 0, 2, 2><<<nbox * 2 * 2, 256, 0, stream>>>(T1, rp + oDa, bDa, T2, bxs, wl, wb6);
    // fused Db+relu -> F+relu -> box-mean
    fuse_box<<<nbox, 256, 0, stream>>>(
        T2, rp + oDbP, bDb, rp + oFP, bF, bxs,
        ((float*)d_out) + (size_t)a0 * 50 * 256);
  }
}